// Round 2
// baseline (173.763 us; speedup 1.0000x reference)
//
#include <hip/hip_runtime.h>
#include <hip/hip_bf16.h>

// Dims
#define Bn 16
#define Dd 256
#define Nn 4096
#define Hh 4
#define Kk 16
#define Vv 64
#define Rr 23
#define Cc 144   // 64 q + 16 k + 64 v

// ---------------- Kernel 1: pack BN-folded weights ----------------
__global__ __launch_bounds__(256) void pack_kernel(
    const float* __restrict__ Wq, const float* __restrict__ qg, const float* __restrict__ qb,
    const float* __restrict__ qm, const float* __restrict__ qv,
    const float* __restrict__ Wk, const float* __restrict__ Wv,
    const float* __restrict__ vg, const float* __restrict__ vb,
    const float* __restrict__ vm, const float* __restrict__ vvar,
    float* __restrict__ Wc, float* __restrict__ bias) {
    int c = blockIdx.x;       // 0..143
    int d = threadIdx.x;      // 0..255
    float scale, bs;
    const float* src;
    if (c < 64) {
        scale = qg[c] * rsqrtf(qv[c] + 1e-5f);
        bs = qb[c] - qm[c] * scale;
        src = Wq + c * Dd;
    } else if (c < 80) {
        scale = 1.f; bs = 0.f;
        src = Wk + (c - 64) * Dd;
    } else {
        int j = c - 80;
        scale = vg[j] * rsqrtf(vvar[j] + 1e-5f);
        bs = vb[j] - vm[j] * scale;
        src = Wv + j * Dd;
    }
    Wc[c * Dd + d] = src[d] * scale;
    if (d == 0) bias[c] = bs;
}

// ---------------- Kernel 2: projection GEMM y[b][144][4096] ----------------
// C[144][128-tile] = Wc[144][256] * x[b][256][128-tile], fp32, thread tile 9x8
#define TKp 32
__global__ __launch_bounds__(256) void proj_kernel(
    const float* __restrict__ x, const float* __restrict__ Wc,
    const float* __restrict__ bias, float* __restrict__ y) {
    __shared__ float Xs[TKp][132];      // padded, 16B-aligned rows
    __shared__ float Ws[Cc][TKp + 1];
    int b = blockIdx.y;
    int n0 = blockIdx.x * 128;
    int t = threadIdx.x;
    int tx = t & 15;       // 0..15 -> col group (8 cols)
    int ty = t >> 4;       // 0..15 -> row group (9 rows)
    const float* xb = x + (size_t)b * Dd * Nn;

    float acc[9][8];
#pragma unroll
    for (int i = 0; i < 9; i++)
#pragma unroll
        for (int j = 0; j < 8; j++) acc[i][j] = 0.f;

    for (int d0 = 0; d0 < Dd; d0 += TKp) {
        // stage X tile: 32 x 128
#pragma unroll
        for (int i = 0; i < 16; i++) {
            int idx = t + 256 * i;
            int dl = idx >> 7, nl = idx & 127;
            Xs[dl][nl] = xb[(size_t)(d0 + dl) * Nn + n0 + nl];
        }
        // stage W tile: 144 x 32
#pragma unroll
        for (int i = 0; i < 18; i++) {
            int idx = t + 256 * i;
            int c = idx >> 5, kd = idx & 31;
            Ws[c][kd] = Wc[c * Dd + d0 + kd];
        }
        __syncthreads();
        for (int kd = 0; kd < TKp; kd++) {
            float a[9], bb[8];
#pragma unroll
            for (int i = 0; i < 9; i++) a[i] = Ws[ty * 9 + i][kd];
#pragma unroll
            for (int j = 0; j < 8; j++) bb[j] = Xs[kd][tx * 8 + j];
#pragma unroll
            for (int i = 0; i < 9; i++)
#pragma unroll
                for (int j = 0; j < 8; j++) acc[i][j] += a[i] * bb[j];
        }
        __syncthreads();
    }
#pragma unroll
    for (int i = 0; i < 9; i++) {
        int c = ty * 9 + i;
        float bs = bias[c];
        float* yp = y + ((size_t)b * Cc + c) * Nn + n0 + tx * 8;
#pragma unroll
        for (int j = 0; j < 8; j++) yp[j] = acc[i][j] + bs;
    }
}

// ---------------- Kernel 3: softmax over n for k channels ----------------
__global__ __launch_bounds__(256) void softmax_kernel(float* __restrict__ y) {
    int b = blockIdx.y, kc = blockIdx.x;
    float* row = y + ((size_t)b * Cc + 64 + kc) * Nn;
    int t = threadIdx.x;
    float vals[16];
    float m = -1e30f;
#pragma unroll
    for (int i = 0; i < 16; i++) {
        vals[i] = row[t + 256 * i];
        m = fmaxf(m, vals[i]);
    }
#pragma unroll
    for (int off = 32; off; off >>= 1) m = fmaxf(m, __shfl_xor(m, off));
    __shared__ float sm[4], ss[4];
    int wave = t >> 6;
    if ((t & 63) == 0) sm[wave] = m;
    __syncthreads();
    m = fmaxf(fmaxf(sm[0], sm[1]), fmaxf(sm[2], sm[3]));
    float s = 0.f;
#pragma unroll
    for (int i = 0; i < 16; i++) {
        vals[i] = __expf(vals[i] - m);
        s += vals[i];
    }
#pragma unroll
    for (int off = 32; off; off >>= 1) s += __shfl_xor(s, off);
    if ((t & 63) == 0) ss[wave] = s;
    __syncthreads();
    s = ss[0] + ss[1] + ss[2] + ss[3];
    float inv = 1.f / s;
#pragma unroll
    for (int i = 0; i < 16; i++) row[t + 256 * i] = vals[i] * inv;
}

// ---------------- Kernel 4: lam_c[b][16][64] = sum_n kk*vv ----------------
#define NCHUNK 128
__global__ __launch_bounds__(256) void lamc_kernel(
    const float* __restrict__ y, float* __restrict__ lam) {
    int b = blockIdx.y, ch = blockIdx.x;
    int n0 = ch * NCHUNK;
    __shared__ float kks[Kk][NCHUNK + 1];
    __shared__ float vvs[Vv][NCHUNK + 1];
    const float* yb = y + (size_t)b * Cc * Nn;
    int t = threadIdx.x;
#pragma unroll
    for (int i = 0; i < (Kk * NCHUNK) / 256; i++) {
        int idx = t + 256 * i;
        int r = idx >> 7, n = idx & 127;
        kks[r][n] = yb[(size_t)(64 + r) * Nn + n0 + n];
    }
#pragma unroll
    for (int i = 0; i < (Vv * NCHUNK) / 256; i++) {
        int idx = t + 256 * i;
        int r = idx >> 7, n = idx & 127;
        vvs[r][n] = yb[(size_t)(80 + r) * Nn + n0 + n];
    }
    __syncthreads();
    int v = t & 63;
    int k0 = t >> 6;   // 0..3
    float acc[4] = {0.f, 0.f, 0.f, 0.f};
    for (int n = 0; n < NCHUNK; n++) {
        float w = vvs[v][n];
#pragma unroll
        for (int j = 0; j < 4; j++) acc[j] += kks[k0 + 4 * j][n] * w;
    }
#pragma unroll
    for (int j = 0; j < 4; j++)
        atomicAdd(&lam[((size_t)b * Kk + k0 + 4 * j) * Vv + v], acc[j]);
}

// ---------------- Kernel 5: fused position-lambda + apply ----------------
#define TN 32
__global__ __launch_bounds__(256) void fused_out_kernel(
    const float* __restrict__ y, const float* __restrict__ lam,
    const float* __restrict__ conv_w, const float* __restrict__ conv_b,
    float* __restrict__ out) {
    int b = blockIdx.y;
    int n0 = blockIdx.x * TN;
    __shared__ float vvs[Vv][TN + 23];     // halo 11 each side -> 54 cols (+1 pad)
    __shared__ float qs[64][TN + 1];
    __shared__ float gs[Hh][Rr][TN + 1];
    __shared__ float lcs[Kk][Vv];
    __shared__ float cws[Kk][Rr];
    int t = threadIdx.x;
    const float* yb = y + (size_t)b * Cc * Nn;

    // FIX: Kk*Rr = 368 > 256 threads -> must stride, else cws[>=256] is garbage
    for (int i = t; i < Kk * Rr; i += 256) cws[i / Rr][i % Rr] = conv_w[i];
    for (int i = t; i < Kk * Vv; i += 256) {
        int k = i >> 6, v = i & 63;
        lcs[k][v] = lam[((size_t)b * Kk + k) * Vv + v] + conv_b[k];
    }
    for (int i = t; i < 64 * TN; i += 256) {
        int c = i >> 5, nl = i & 31;
        qs[c][nl] = yb[(size_t)c * Nn + n0 + nl];
    }
    for (int i = t; i < Vv * (TN + 22); i += 256) {
        int v = i / (TN + 22), j = i % (TN + 22);
        int n = n0 + j - 11;
        vvs[v][j] = (n >= 0 && n < Nn) ? yb[(size_t)(80 + v) * Nn + n] : 0.f;
    }
    __syncthreads();
    // g[h][r][nl] = sum_k q[h*16+k][nl] * cw[k][r]
    for (int i = t; i < Hh * Rr * TN; i += 256) {
        int h = i / (Rr * TN);
        int r = (i / TN) % Rr;
        int nl = i % TN;
        float g = 0.f;
#pragma unroll
        for (int k = 0; k < Kk; k++) g += qs[h * 16 + k][nl] * cws[k][r];
        gs[h][r][nl] = g;
    }
    __syncthreads();

    int nl = t & (TN - 1);
    int vbase = (t >> 5) * 8;
    float acc[4][8];
#pragma unroll
    for (int h = 0; h < 4; h++)
#pragma unroll
        for (int vl = 0; vl < 8; vl++) acc[h][vl] = 0.f;

#pragma unroll
    for (int r = 0; r < Rr; r++) {
        float g0 = gs[0][r][nl], g1 = gs[1][r][nl], g2 = gs[2][r][nl], g3 = gs[3][r][nl];
#pragma unroll
        for (int vl = 0; vl < 8; vl++) {
            float wv = vvs[vbase + vl][nl + r];
            acc[0][vl] += g0 * wv;
            acc[1][vl] += g1 * wv;
            acc[2][vl] += g2 * wv;
            acc[3][vl] += g3 * wv;
        }
    }
#pragma unroll
    for (int k = 0; k < Kk; k++) {
        float q0 = qs[k][nl], q1 = qs[16 + k][nl], q2 = qs[32 + k][nl], q3 = qs[48 + k][nl];
#pragma unroll
        for (int vl = 0; vl < 8; vl++) {
            float lc = lcs[k][vbase + vl];
            acc[0][vl] += q0 * lc;
            acc[1][vl] += q1 * lc;
            acc[2][vl] += q2 * lc;
            acc[3][vl] += q3 * lc;
        }
    }
    float* ob = out + (size_t)b * 256 * Nn + n0 + nl;
#pragma unroll
    for (int h = 0; h < 4; h++)
#pragma unroll
        for (int vl = 0; vl < 8; vl++)
            ob[(size_t)(h * 64 + vbase + vl) * Nn] = acc[h][vl];
}

extern "C" void kernel_launch(void* const* d_in, const int* in_sizes, int n_in,
                              void* d_out, int out_size, void* d_ws, size_t ws_size,
                              hipStream_t stream) {
    const float* x      = (const float*)d_in[0];
    const float* Wq     = (const float*)d_in[1];
    const float* qg     = (const float*)d_in[2];
    const float* qb     = (const float*)d_in[3];
    const float* qm     = (const float*)d_in[4];
    const float* qv     = (const float*)d_in[5];
    const float* Wk     = (const float*)d_in[6];
    const float* Wv     = (const float*)d_in[7];
    const float* vg     = (const float*)d_in[8];
    const float* vb     = (const float*)d_in[9];
    const float* vm     = (const float*)d_in[10];
    const float* vvar   = (const float*)d_in[11];
    const float* conv_w = (const float*)d_in[12];
    const float* conv_b = (const float*)d_in[13];
    float* out = (float*)d_out;

    float* ws   = (float*)d_ws;
    float* Wc   = ws;                        // 144*256      = 36864 floats
    float* bias = ws + 36864;                // 144 floats
    float* y    = ws + 37120;                // 16*144*4096  = 9,437,184 floats
    float* lam  = y + (size_t)Bn * Cc * Nn;  // 16*16*64     = 16384 floats

    pack_kernel<<<Cc, 256, 0, stream>>>(Wq, qg, qb, qm, qv, Wk, Wv, vg, vb, vm, vvar, Wc, bias);
    proj_kernel<<<dim3(Nn / 128, Bn), 256, 0, stream>>>(x, Wc, bias, y);
    softmax_kernel<<<dim3(Kk, Bn), 256, 0, stream>>>(y);
    hipMemsetAsync(lam, 0, (size_t)Bn * Kk * Vv * sizeof(float), stream);
    lamc_kernel<<<dim3(Nn / NCHUNK, Bn), 256, 0, stream>>>(y, lam);
    fused_out_kernel<<<dim3(Nn / TN, Bn), 256, 0, stream>>>(y, lam, conv_w, conv_b, out);
}

// Round 3
// 96.628 us; speedup vs baseline: 1.7983x; 1.7983x over previous
//
#include <hip/hip_runtime.h>
#include <hip/hip_bf16.h>

typedef unsigned int uint;
typedef unsigned short ushort;

// Dims
#define Bn 16
#define Dd 256
#define Nn 4096
#define Hh 4
#define Kk 16
#define Vv 64
#define Rr 23
#define Cc 144   // 64 q + 16 k + 64 v

typedef short bf16x8s __attribute__((ext_vector_type(8)));
typedef float f32x4 __attribute__((ext_vector_type(4)));

static __device__ __forceinline__ ushort f2bf(float f) {
    __hip_bfloat16 h = __float2bfloat16(f);
    return __builtin_bit_cast(ushort, h);
}

// ---------------- Kernel 1: pack BN-folded weights (bf16, A-fragment order) ----------------
// Fragment order for mfma_f32_16x16x32_bf16 A-operand:
//   c = rt*16 + lm (lm = lane&15), d = kk*32 + hi*8 + j (hi = lane>>4, j = 0..7)
//   Wf16[ ((rt*8+kk)*64 + hi*16+lm)*8 + j ]
__global__ __launch_bounds__(256) void pack_kernel(
    const float* __restrict__ Wq, const float* __restrict__ qg, const float* __restrict__ qb,
    const float* __restrict__ qm, const float* __restrict__ qv,
    const float* __restrict__ Wk, const float* __restrict__ Wv,
    const float* __restrict__ vg, const float* __restrict__ vb,
    const float* __restrict__ vm, const float* __restrict__ vvar,
    ushort* __restrict__ Wf16, float* __restrict__ bias) {
    int c = blockIdx.x;       // 0..143
    int d = threadIdx.x;      // 0..255
    float scale, bs;
    const float* src;
    if (c < 64) {
        scale = qg[c] * rsqrtf(qv[c] + 1e-5f);
        bs = qb[c] - qm[c] * scale;
        src = Wq + c * Dd;
    } else if (c < 80) {
        scale = 1.f; bs = 0.f;
        src = Wk + (c - 64) * Dd;
    } else {
        int j = c - 80;
        scale = vg[j] * rsqrtf(vvar[j] + 1e-5f);
        bs = vb[j] - vm[j] * scale;
        src = Wv + j * Dd;
    }
    int rt = c >> 4, lm = c & 15;
    int kk = d >> 5, hi = (d >> 3) & 3, j = d & 7;
    int idx = ((rt * 8 + kk) * 64 + hi * 16 + lm) * 8 + j;
    Wf16[idx] = f2bf(src[d] * scale);
    if (d == 0) bias[c] = bs;
}

// ---------------- Kernel 2: MFMA projection y[b][144][4096] ----------------
// Per block: full 144-row output x 64-col n-tile. 4 waves, wave w owns cols w*16..+15.
// W staged in LDS in fragment order (two K-phases of 4 ksteps, 36.9KB).
// X fragments loaded direct global->reg with fp32->bf16 convert.
__global__ __launch_bounds__(256, 4) void proj_mfma_kernel(
    const float* __restrict__ x, const ushort* __restrict__ Wf16,
    const float* __restrict__ bias, float* __restrict__ y) {
    __shared__ ushort Wlds[9 * 4 * 64 * 8];   // 36 frag-groups x 64 lanes x 8 bf16 = 36864 B

    int b = blockIdx.y;
    int n0 = blockIdx.x * 64;
    int t = threadIdx.x;
    int w = t >> 6;            // wave 0..3
    int l = t & 63;
    int lm = l & 15;
    int hi = l >> 4;           // 0..3
    int n = n0 + w * 16 + lm;  // this lane's output column

    const uint* WfU = (const uint*)Wf16;
    uint* WldsU = (uint*)Wlds;

    f32x4 acc[9];
#pragma unroll
    for (int rt = 0; rt < 9; rt++) acc[rt] = (f32x4){0.f, 0.f, 0.f, 0.f};

    const float* xb = x + (size_t)b * Dd * Nn + n;

#pragma unroll
    for (int p = 0; p < 2; p++) {
        int kb = p * 4;
        if (p) __syncthreads();   // previous phase compute done before overwrite
        // stage W fragments for ksteps kb..kb+3: 9216 dwords
#pragma unroll
        for (int i = 0; i < 36; i++) {
            int flat = t + 256 * i;
            int f2 = flat >> 8;        // rt*4 + kkl
            int within = flat & 255;
            int rt = f2 >> 2, kkl = f2 & 3;
            WldsU[flat] = WfU[((rt * 8 + kb + kkl) << 8) + within];
        }
        __syncthreads();

#pragma unroll
        for (int kkl = 0; kkl < 4; kkl++) {
            int kk = kb + kkl;
            // B fragment: 8 strided global loads, cvt to bf16
            const float* xp = xb + (size_t)(kk * 32 + hi * 8) * Nn;
            float f[8];
#pragma unroll
            for (int j = 0; j < 8; j++) f[j] = xp[(size_t)j * Nn];
            bf16x8s bfrag;
#pragma unroll
            for (int j = 0; j < 8; j++) bfrag[j] = (short)f2bf(f[j]);
#pragma unroll
            for (int rt = 0; rt < 9; rt++) {
                bf16x8s afrag = *reinterpret_cast<const bf16x8s*>(
                    &Wlds[(size_t)((rt * 4 + kkl) * 64 + l) * 8]);
                acc[rt] = __builtin_amdgcn_mfma_f32_16x16x32_bf16(afrag, bfrag, acc[rt], 0, 0, 0);
            }
        }
    }

    // epilogue: c = rt*16 + hi*4 + r, col n
    float* yb = y + (size_t)b * Cc * Nn + n;
#pragma unroll
    for (int rt = 0; rt < 9; rt++) {
#pragma unroll
        for (int r = 0; r < 4; r++) {
            int c = rt * 16 + hi * 4 + r;
            yb[(size_t)c * Nn] = acc[rt][r] + bias[c];
        }
    }
}

// ---------------- Kernel 3: softmax over n for k channels ----------------
__global__ __launch_bounds__(256) void softmax_kernel(float* __restrict__ y) {
    int b = blockIdx.y, kc = blockIdx.x;
    float* row = y + ((size_t)b * Cc + 64 + kc) * Nn;
    int t = threadIdx.x;
    float vals[16];
    float m = -1e30f;
#pragma unroll
    for (int i = 0; i < 16; i++) {
        vals[i] = row[t + 256 * i];
        m = fmaxf(m, vals[i]);
    }
#pragma unroll
    for (int off = 32; off; off >>= 1) m = fmaxf(m, __shfl_xor(m, off));
    __shared__ float sm[4], ss[4];
    int wave = t >> 6;
    if ((t & 63) == 0) sm[wave] = m;
    __syncthreads();
    m = fmaxf(fmaxf(sm[0], sm[1]), fmaxf(sm[2], sm[3]));
    float s = 0.f;
#pragma unroll
    for (int i = 0; i < 16; i++) {
        vals[i] = __expf(vals[i] - m);
        s += vals[i];
    }
#pragma unroll
    for (int off = 32; off; off >>= 1) s += __shfl_xor(s, off);
    if ((t & 63) == 0) ss[wave] = s;
    __syncthreads();
    s = ss[0] + ss[1] + ss[2] + ss[3];
    float inv = 1.f / s;
#pragma unroll
    for (int i = 0; i < 16; i++) row[t + 256 * i] = vals[i] * inv;
}

// ---------------- Kernel 4: lam_c[b][16][64] = sum_n kk*vv ----------------
#define NCHUNK 128
__global__ __launch_bounds__(256) void lamc_kernel(
    const float* __restrict__ y, float* __restrict__ lam) {
    int b = blockIdx.y, ch = blockIdx.x;
    int n0 = ch * NCHUNK;
    __shared__ float kks[Kk][NCHUNK + 1];
    __shared__ float vvs[Vv][NCHUNK + 1];
    const float* yb = y + (size_t)b * Cc * Nn;
    int t = threadIdx.x;
#pragma unroll
    for (int i = 0; i < (Kk * NCHUNK) / 256; i++) {
        int idx = t + 256 * i;
        int r = idx >> 7, n = idx & 127;
        kks[r][n] = yb[(size_t)(64 + r) * Nn + n0 + n];
    }
#pragma unroll
    for (int i = 0; i < (Vv * NCHUNK) / 256; i++) {
        int idx = t + 256 * i;
        int r = idx >> 7, n = idx & 127;
        vvs[r][n] = yb[(size_t)(80 + r) * Nn + n0 + n];
    }
    __syncthreads();
    int v = t & 63;
    int k0 = t >> 6;   // 0..3
    float acc[4] = {0.f, 0.f, 0.f, 0.f};
    for (int n = 0; n < NCHUNK; n++) {
        float wv = vvs[v][n];
#pragma unroll
        for (int j = 0; j < 4; j++) acc[j] += kks[k0 + 4 * j][n] * wv;
    }
#pragma unroll
    for (int j = 0; j < 4; j++)
        atomicAdd(&lam[((size_t)b * Kk + k0 + 4 * j) * Vv + v], acc[j]);
}

// ---------------- Kernel 5: fused position-lambda + apply ----------------
#define TN 32
__global__ __launch_bounds__(256) void fused_out_kernel(
    const float* __restrict__ y, const float* __restrict__ lam,
    const float* __restrict__ conv_w, const float* __restrict__ conv_b,
    float* __restrict__ out) {
    int b = blockIdx.y;
    int n0 = blockIdx.x * TN;
    __shared__ float vvs[Vv][TN + 23];     // halo 11 each side -> 54 cols (+1 pad)
    __shared__ float qs[64][TN + 1];
    __shared__ float gs[Hh][Rr][TN + 1];
    __shared__ float lcs[Kk][Vv];
    __shared__ float cws[Kk][Rr];
    int t = threadIdx.x;
    const float* yb = y + (size_t)b * Cc * Nn;

    for (int i = t; i < Kk * Rr; i += 256) cws[i / Rr][i % Rr] = conv_w[i];
    for (int i = t; i < Kk * Vv; i += 256) {
        int k = i >> 6, v = i & 63;
        lcs[k][v] = lam[((size_t)b * Kk + k) * Vv + v] + conv_b[k];
    }
    for (int i = t; i < 64 * TN; i += 256) {
        int c = i >> 5, nl = i & 31;
        qs[c][nl] = yb[(size_t)c * Nn + n0 + nl];
    }
    for (int i = t; i < Vv * (TN + 22); i += 256) {
        int v = i / (TN + 22), j = i % (TN + 22);
        int n = n0 + j - 11;
        vvs[v][j] = (n >= 0 && n < Nn) ? yb[(size_t)(80 + v) * Nn + n] : 0.f;
    }
    __syncthreads();
    // g[h][r][nl] = sum_k q[h*16+k][nl] * cw[k][r]
    for (int i = t; i < Hh * Rr * TN; i += 256) {
        int h = i / (Rr * TN);
        int r = (i / TN) % Rr;
        int nl = i % TN;
        float g = 0.f;
#pragma unroll
        for (int k = 0; k < Kk; k++) g += qs[h * 16 + k][nl] * cws[k][r];
        gs[h][r][nl] = g;
    }
    __syncthreads();

    int nl = t & (TN - 1);
    int vbase = (t >> 5) * 8;
    float acc[4][8];
#pragma unroll
    for (int h = 0; h < 4; h++)
#pragma unroll
        for (int vl = 0; vl < 8; vl++) acc[h][vl] = 0.f;

#pragma unroll
    for (int r = 0; r < Rr; r++) {
        float g0 = gs[0][r][nl], g1 = gs[1][r][nl], g2 = gs[2][r][nl], g3 = gs[3][r][nl];
#pragma unroll
        for (int vl = 0; vl < 8; vl++) {
            float wv = vvs[vbase + vl][nl + r];
            acc[0][vl] += g0 * wv;
            acc[1][vl] += g1 * wv;
            acc[2][vl] += g2 * wv;
            acc[3][vl] += g3 * wv;
        }
    }
#pragma unroll
    for (int k = 0; k < Kk; k++) {
        float q0 = qs[k][nl], q1 = qs[16 + k][nl], q2 = qs[32 + k][nl], q3 = qs[48 + k][nl];
#pragma unroll
        for (int vl = 0; vl < 8; vl++) {
            float lc = lcs[k][vbase + vl];
            acc[0][vl] += q0 * lc;
            acc[1][vl] += q1 * lc;
            acc[2][vl] += q2 * lc;
            acc[3][vl] += q3 * lc;
        }
    }
    float* ob = out + (size_t)b * 256 * Nn + n0 + nl;
#pragma unroll
    for (int h = 0; h < 4; h++)
#pragma unroll
        for (int vl = 0; vl < 8; vl++)
            ob[(size_t)(h * 64 + vbase + vl) * Nn] = acc[h][vl];
}

extern "C" void kernel_launch(void* const* d_in, const int* in_sizes, int n_in,
                              void* d_out, int out_size, void* d_ws, size_t ws_size,
                              hipStream_t stream) {
    const float* x      = (const float*)d_in[0];
    const float* Wq     = (const float*)d_in[1];
    const float* qg     = (const float*)d_in[2];
    const float* qb     = (const float*)d_in[3];
    const float* qm     = (const float*)d_in[4];
    const float* qv     = (const float*)d_in[5];
    const float* Wk     = (const float*)d_in[6];
    const float* Wv     = (const float*)d_in[7];
    const float* vg     = (const float*)d_in[8];
    const float* vb     = (const float*)d_in[9];
    const float* vm     = (const float*)d_in[10];
    const float* vvar   = (const float*)d_in[11];
    const float* conv_w = (const float*)d_in[12];
    const float* conv_b = (const float*)d_in[13];
    float* out = (float*)d_out;

    float* wsf = (float*)d_ws;
    ushort* Wf16 = (ushort*)wsf;                 // 36864 ushort = 18432 floats
    float* bias  = wsf + 18432;                  // 144 floats
    float* y     = wsf + 18432 + 256;            // 16*144*4096 floats
    float* lam   = y + (size_t)Bn * Cc * Nn;     // 16*16*64 floats

    pack_kernel<<<Cc, 256, 0, stream>>>(Wq, qg, qb, qm, qv, Wk, Wv, vg, vb, vm, vvar, Wf16, bias);
    proj_mfma_kernel<<<dim3(Nn / 64, Bn), 256, 0, stream>>>(x, Wf16, bias, y);
    softmax_kernel<<<dim3(Kk, Bn), 256, 0, stream>>>(y);
    hipMemsetAsync(lam, 0, (size_t)Bn * Kk * Vv * sizeof(float), stream);
    lamc_kernel<<<dim3(Nn / NCHUNK, Bn), 256, 0, stream>>>(y, lam);
    fused_out_kernel<<<dim3(Nn / TN, Bn), 256, 0, stream>>>(y, lam, conv_w, conv_b, out);
}